// Round 4
// baseline (1019.861 us; speedup 1.0000x reference)
//
#include <hip/hip_runtime.h>
#include <math.h>

typedef __bf16 bf16;
typedef __attribute__((ext_vector_type(8))) __bf16 bf16x8;
typedef __attribute__((ext_vector_type(4))) float f32x4;

// ---------------- embedding: x0 = concat(emb_deg[deg], emb_lab[lab]) as bf16 ----------------
__global__ __launch_bounds__(256) void embed_kernel(
    const int* __restrict__ deg, const int* __restrict__ lab,
    const float* __restrict__ ed, const float* __restrict__ el,
    bf16* __restrict__ x0, int n) {
  int idx = blockIdx.x * 256 + threadIdx.x;  // one 8-elem chunk per thread
  if (idx >= n * 16) return;                 // 128 elems = 16 chunks per node
  int node = idx >> 4, q = idx & 15;
  const float* srcp = (q < 8) ? (ed + (size_t)deg[node] * 64 + q * 8)
                              : (el + (size_t)lab[node] * 64 + (q - 8) * 8);
  float4 a = ((const float4*)srcp)[0];
  float4 b = ((const float4*)srcp)[1];
  union { bf16 h[8]; uint4 u; } out;
  out.h[0] = (bf16)a.x; out.h[1] = (bf16)a.y; out.h[2] = (bf16)a.z; out.h[3] = (bf16)a.w;
  out.h[4] = (bf16)b.x; out.h[5] = (bf16)b.y; out.h[6] = (bf16)b.z; out.h[7] = (bf16)b.w;
  *(uint4*)(x0 + (size_t)idx * 8) = out.u;
}

// ---------------- CSR build ----------------
__global__ __launch_bounds__(256) void hist_kernel(const int* __restrict__ dst,
                                                   int* __restrict__ counts, int E) {
  int e = blockIdx.x * 256 + threadIdx.x;
  if (e < E) atomicAdd(&counts[dst[e]], 1);
}

__global__ __launch_bounds__(256) void scan1_kernel(const int* __restrict__ counts,
                                                    int* __restrict__ rowptr,
                                                    int* __restrict__ bsums, int n) {
  __shared__ int lds[256];
  int tid = threadIdx.x;
  int base = blockIdx.x * 2048;
  int vals[8];
  int s = 0;
#pragma unroll
  for (int k = 0; k < 8; ++k) {
    int idx = base + tid * 8 + k;
    vals[k] = (idx < n) ? counts[idx] : 0;
    s += vals[k];
  }
  lds[tid] = s;
  __syncthreads();
  for (int off = 1; off < 256; off <<= 1) {
    int v = (tid >= off) ? lds[tid - off] : 0;
    __syncthreads();
    lds[tid] += v;
    __syncthreads();
  }
  int run = lds[tid] - s;
#pragma unroll
  for (int k = 0; k < 8; ++k) {
    int idx = base + tid * 8 + k;
    run += vals[k];
    if (idx < n) rowptr[idx + 1] = run;
  }
  if (tid == 255) bsums[blockIdx.x] = lds[255];
}

__global__ void scan2_kernel(const int* __restrict__ bsums, int* __restrict__ boffs, int nb) {
  if (threadIdx.x == 0) {
    int run = 0;
    for (int i = 0; i < nb; ++i) { boffs[i] = run; run += bsums[i]; }
  }
}

__global__ __launch_bounds__(256) void scan3_kernel(int* __restrict__ rowptr,
                                                    const int* __restrict__ boffs, int n) {
  int idx = blockIdx.x * 256 + threadIdx.x;
  if (idx == 0) rowptr[0] = 0;
  if (idx < n) rowptr[idx + 1] += boffs[idx >> 11];
}

// cursor[i] = rowptr[i] (nodes); bcur[b] = rowptr[b*128] (buckets)
__global__ __launch_bounds__(256) void cursor_kernel(int* __restrict__ cursor,
                                                     int* __restrict__ bcur,
                                                     const int* __restrict__ rowptr,
                                                     int n, int nbuck) {
  int idx = blockIdx.x * 256 + threadIdx.x;
  if (idx < n) cursor[idx] = rowptr[idx];
  if (idx < nbuck) bcur[idx] = rowptr[idx << 7];
}

// pass A: bin edges by dst>>7; per-bucket streams are append-only -> sequential writes
__global__ __launch_bounds__(256) void binpass_kernel(const int* __restrict__ src,
                                                      const int* __restrict__ dst,
                                                      int* __restrict__ bcur,
                                                      int2* __restrict__ binned, int E) {
  int e = blockIdx.x * 256 + threadIdx.x;
  if (e < E) {
    int d = dst[e];
    int pos = atomicAdd(&bcur[d >> 7], 1);
    binned[pos] = make_int2(src[e], d);
  }
}

// pass B: scatter to colidx; consecutive binned edges share a bucket -> 8KB write window
__global__ __launch_bounds__(256) void scatter2_kernel(const int2* __restrict__ binned,
                                                       int* __restrict__ cursor,
                                                       int* __restrict__ colidx, int E) {
  int i = blockIdx.x * 256 + threadIdx.x;
  if (i < E) {
    int2 p = binned[i];
    int pos = atomicAdd(&cursor[p.y], 1);
    colidx[pos] = p.x;
  }
}

// ---------------- MFMA GEMM 0: y = x0(bf16) @ W0^T, bf16 out ----------------
__global__ __launch_bounds__(256) void mfma_gemm0(
    const bf16* __restrict__ x, const float* __restrict__ W,
    bf16* __restrict__ y, int n) {
  __shared__ bf16 As[64][136];  // [node][d]
  __shared__ bf16 Bs[64][136];  // [o][d]
  int tid = threadIdx.x;
  int nbase = blockIdx.x * 64;
  {
    int r = tid >> 2, c = tid & 3;  // r: row, c: 32-elem chunk
    int node = nbase + r;
    uint4 v[4] = {};
    if (node < n) {
      const uint4* p = (const uint4*)(x + (size_t)node * 128 + c * 32);
#pragma unroll
      for (int j = 0; j < 4; ++j) v[j] = p[j];
    }
#pragma unroll
    for (int j = 0; j < 4; ++j) *(uint4*)&As[r][c * 32 + j * 8] = v[j];
    const float4* wp = (const float4*)(W + r * 128 + c * 32);
#pragma unroll
    for (int j = 0; j < 4; ++j) {
      float4 f0 = wp[j * 2], f1 = wp[j * 2 + 1];
      union { bf16 h[8]; uint4 u; } t;
      t.h[0] = (bf16)f0.x; t.h[1] = (bf16)f0.y; t.h[2] = (bf16)f0.z; t.h[3] = (bf16)f0.w;
      t.h[4] = (bf16)f1.x; t.h[5] = (bf16)f1.y; t.h[6] = (bf16)f1.z; t.h[7] = (bf16)f1.w;
      *(uint4*)&Bs[r][c * 32 + j * 8] = t.u;
    }
  }
  __syncthreads();
  int l = tid & 63, w = tid >> 6, m = l & 15, quad = l >> 4;
  f32x4 acc[4] = {{0.f, 0.f, 0.f, 0.f}, {0.f, 0.f, 0.f, 0.f},
                  {0.f, 0.f, 0.f, 0.f}, {0.f, 0.f, 0.f, 0.f}};
#pragma unroll
  for (int k0 = 0; k0 < 128; k0 += 32) {
    bf16x8 a = *(const bf16x8*)&As[w * 16 + m][k0 + quad * 8];
#pragma unroll
    for (int t = 0; t < 4; ++t) {
      bf16x8 b = *(const bf16x8*)&Bs[t * 16 + m][k0 + quad * 8];
      acc[t] = __builtin_amdgcn_mfma_f32_16x16x32_bf16(a, b, acc[t], 0, 0, 0);
    }
  }
#pragma unroll
  for (int t = 0; t < 4; ++t)
#pragma unroll
    for (int r4 = 0; r4 < 4; ++r4) {
      int node = nbase + w * 16 + quad * 4 + r4;
      if (node < n) y[(size_t)node * 64 + t * 16 + m] = (bf16)acc[t][r4];
    }
}

// ------- MFMA GEMM (layers 1,2): z = leaky(bn(hin)) [bf16 out]; y = z @ W^T [bf16 out] -------
__global__ __launch_bounds__(256) void mfma_gemm_bn(
    const float* __restrict__ hin, const float* __restrict__ st,
    const float* __restrict__ W, bf16* __restrict__ z,
    bf16* __restrict__ y, int n) {
  __shared__ bf16 As[64][72];
  __shared__ bf16 Bs[64][72];
  int tid = threadIdx.x;
  int nbase = blockIdx.x * 64;
  {
    int r = tid >> 2, c = tid & 3;  // 16-elem chunk
    int node = nbase + r;
    union { bf16 h[16]; uint4 u[2]; } t;
    if (node < n) {
      const float4* p = (const float4*)(hin + (size_t)node * 64 + c * 16);
#pragma unroll
      for (int j = 0; j < 4; ++j) {
        float4 f = p[j];
        int d = c * 16 + j * 4;
        float v0 = f.x * st[128 + d] + st[192 + d];
        float v1 = f.y * st[129 + d] + st[193 + d];
        float v2 = f.z * st[130 + d] + st[194 + d];
        float v3 = f.w * st[131 + d] + st[195 + d];
        v0 = (v0 >= 0.f) ? v0 : 0.01f * v0;
        v1 = (v1 >= 0.f) ? v1 : 0.01f * v1;
        v2 = (v2 >= 0.f) ? v2 : 0.01f * v2;
        v3 = (v3 >= 0.f) ? v3 : 0.01f * v3;
        t.h[j * 4 + 0] = (bf16)v0; t.h[j * 4 + 1] = (bf16)v1;
        t.h[j * 4 + 2] = (bf16)v2; t.h[j * 4 + 3] = (bf16)v3;
      }
      *(uint4*)(z + (size_t)node * 64 + c * 16) = t.u[0];
      *(uint4*)(z + (size_t)node * 64 + c * 16 + 8) = t.u[1];
    } else {
      t.u[0] = uint4{0, 0, 0, 0}; t.u[1] = uint4{0, 0, 0, 0};
    }
    *(uint4*)&As[r][c * 16] = t.u[0];
    *(uint4*)&As[r][c * 16 + 8] = t.u[1];
    const float4* wp = (const float4*)(W + r * 64 + c * 16);
#pragma unroll
    for (int j = 0; j < 2; ++j) {
      float4 f0 = wp[j * 2], f1 = wp[j * 2 + 1];
      union { bf16 h[8]; uint4 u; } tw;
      tw.h[0] = (bf16)f0.x; tw.h[1] = (bf16)f0.y; tw.h[2] = (bf16)f0.z; tw.h[3] = (bf16)f0.w;
      tw.h[4] = (bf16)f1.x; tw.h[5] = (bf16)f1.y; tw.h[6] = (bf16)f1.z; tw.h[7] = (bf16)f1.w;
      *(uint4*)&Bs[r][c * 16 + j * 8] = tw.u;
    }
  }
  __syncthreads();
  int l = tid & 63, w = tid >> 6, m = l & 15, quad = l >> 4;
  f32x4 acc[4] = {{0.f, 0.f, 0.f, 0.f}, {0.f, 0.f, 0.f, 0.f},
                  {0.f, 0.f, 0.f, 0.f}, {0.f, 0.f, 0.f, 0.f}};
#pragma unroll
  for (int k0 = 0; k0 < 64; k0 += 32) {
    bf16x8 a = *(const bf16x8*)&As[w * 16 + m][k0 + quad * 8];
#pragma unroll
    for (int t = 0; t < 4; ++t) {
      bf16x8 b = *(const bf16x8*)&Bs[t * 16 + m][k0 + quad * 8];
      acc[t] = __builtin_amdgcn_mfma_f32_16x16x32_bf16(a, b, acc[t], 0, 0, 0);
    }
  }
#pragma unroll
  for (int t = 0; t < 4; ++t)
#pragma unroll
    for (int r4 = 0; r4 < 4; ++r4) {
      int node = nbase + w * 16 + quad * 4 + r4;
      if (node < n) y[(size_t)node * 64 + t * 16 + m] = (bf16)acc[t][r4];
    }
}

// ---------------- gather: h = y + csr_sum(y) + b (fp32 acc from bf16 y), BN stats ----------------
__global__ __launch_bounds__(256) void gather_kernel(
    const bf16* __restrict__ y, const int* __restrict__ rowptr,
    const int* __restrict__ colidx, const float* __restrict__ bias,
    float* __restrict__ h, float* __restrict__ stats, int n) {
  __shared__ float s_sum[64], s_sq[64];
  int tid = threadIdx.x;
  if (tid < 64) { s_sum[tid] = 0.f; s_sq[tid] = 0.f; }
  __syncthreads();
  int lane = tid & 63, wv = tid >> 6;
  float bv = bias[lane];
  float psum = 0.f, psq = 0.f;
  int stride = gridDim.x * 4;
  for (int node = blockIdx.x * 4 + wv; node < n; node += stride) {
    float acc = (float)y[(size_t)node * 64 + lane] + bv;
    int beg = rowptr[node], end = rowptr[node + 1];
    int e = beg;
    for (; e + 8 <= end; e += 8) {
      int j0 = colidx[e], j1 = colidx[e + 1], j2 = colidx[e + 2], j3 = colidx[e + 3];
      int j4 = colidx[e + 4], j5 = colidx[e + 5], j6 = colidx[e + 6], j7 = colidx[e + 7];
      float v0 = (float)y[(size_t)j0 * 64 + lane], v1 = (float)y[(size_t)j1 * 64 + lane];
      float v2 = (float)y[(size_t)j2 * 64 + lane], v3 = (float)y[(size_t)j3 * 64 + lane];
      float v4 = (float)y[(size_t)j4 * 64 + lane], v5 = (float)y[(size_t)j5 * 64 + lane];
      float v6 = (float)y[(size_t)j6 * 64 + lane], v7 = (float)y[(size_t)j7 * 64 + lane];
      acc += ((v0 + v1) + (v2 + v3)) + ((v4 + v5) + (v6 + v7));
    }
    for (; e + 4 <= end; e += 4) {
      int j0 = colidx[e], j1 = colidx[e + 1], j2 = colidx[e + 2], j3 = colidx[e + 3];
      float v0 = (float)y[(size_t)j0 * 64 + lane], v1 = (float)y[(size_t)j1 * 64 + lane];
      float v2 = (float)y[(size_t)j2 * 64 + lane], v3 = (float)y[(size_t)j3 * 64 + lane];
      acc += (v0 + v1) + (v2 + v3);
    }
    for (; e < end; ++e) acc += (float)y[(size_t)colidx[e] * 64 + lane];
    h[(size_t)node * 64 + lane] = acc;
    psum += acc;
    psq += acc * acc;
  }
  atomicAdd(&s_sum[lane], psum);
  atomicAdd(&s_sq[lane], psq);
  __syncthreads();
  if (tid < 64) {
    atomicAdd(&stats[tid], s_sum[tid]);
    atomicAdd(&stats[64 + tid], s_sq[tid]);
  }
}

// ---------------- final MLP over concat [x0|z1|z2|bnleaky(h2)] (320 -> 64), MFMA ----------------
__global__ __launch_bounds__(256) void mfma_final(
    const bf16* __restrict__ x0, const bf16* __restrict__ z1,
    const bf16* __restrict__ z2, const float* __restrict__ h2,
    const float* __restrict__ st2, const float* __restrict__ fw1,
    const float* __restrict__ fb1, bf16* __restrict__ hf,
    float* __restrict__ stats, int n) {
  __shared__ bf16 As[64][136];
  __shared__ bf16 Bs[64][136];
  __shared__ float s_sum[64], s_sq[64];
  int tid = threadIdx.x;
  if (tid < 64) { s_sum[tid] = 0.f; s_sq[tid] = 0.f; }
  int nbase = blockIdx.x * 64;
  int l = tid & 63, w = tid >> 6, m = l & 15, quad = l >> 4;
  int r = tid >> 2, c = tid & 3;
  int node_r = nbase + r;
  f32x4 acc[4] = {{0.f, 0.f, 0.f, 0.f}, {0.f, 0.f, 0.f, 0.f},
                  {0.f, 0.f, 0.f, 0.f}, {0.f, 0.f, 0.f, 0.f}};

#pragma unroll
  for (int seg = 0; seg < 4; ++seg) {
    __syncthreads();  // LDS reuse guard
    if (seg == 0) {
      uint4 v[4] = {};
      if (node_r < n) {
        const uint4* p = (const uint4*)(x0 + (size_t)node_r * 128 + c * 32);
#pragma unroll
        for (int j = 0; j < 4; ++j) v[j] = p[j];
      }
#pragma unroll
      for (int j = 0; j < 4; ++j) *(uint4*)&As[r][c * 32 + j * 8] = v[j];
      const float4* wp = (const float4*)(fw1 + r * 320 + c * 32);
#pragma unroll
      for (int j = 0; j < 4; ++j) {
        float4 f0 = wp[j * 2], f1 = wp[j * 2 + 1];
        union { bf16 h[8]; uint4 u; } t;
        t.h[0] = (bf16)f0.x; t.h[1] = (bf16)f0.y; t.h[2] = (bf16)f0.z; t.h[3] = (bf16)f0.w;
        t.h[4] = (bf16)f1.x; t.h[5] = (bf16)f1.y; t.h[6] = (bf16)f1.z; t.h[7] = (bf16)f1.w;
        *(uint4*)&Bs[r][c * 32 + j * 8] = t.u;
      }
    } else if (seg < 3) {
      const bf16* zz = (seg == 1) ? z1 : z2;
      uint4 v[2] = {};
      if (node_r < n) {
        const uint4* p = (const uint4*)(zz + (size_t)node_r * 64 + c * 16);
        v[0] = p[0]; v[1] = p[1];
      }
      *(uint4*)&As[r][c * 16] = v[0];
      *(uint4*)&As[r][c * 16 + 8] = v[1];
      const float4* wp = (const float4*)(fw1 + r * 320 + (seg == 1 ? 128 : 192) + c * 16);
#pragma unroll
      for (int j = 0; j < 2; ++j) {
        float4 f0 = wp[j * 2], f1 = wp[j * 2 + 1];
        union { bf16 h[8]; uint4 u; } t;
        t.h[0] = (bf16)f0.x; t.h[1] = (bf16)f0.y; t.h[2] = (bf16)f0.z; t.h[3] = (bf16)f0.w;
        t.h[4] = (bf16)f1.x; t.h[5] = (bf16)f1.y; t.h[6] = (bf16)f1.z; t.h[7] = (bf16)f1.w;
        *(uint4*)&Bs[r][c * 16 + j * 8] = t.u;
      }
    } else {
      union { bf16 h[16]; uint4 u[2]; } t;
      if (node_r < n) {
        const float4* p = (const float4*)(h2 + (size_t)node_r * 64 + c * 16);
#pragma unroll
        for (int j = 0; j < 4; ++j) {
          float4 f = p[j];
          int d = c * 16 + j * 4;
          float v0 = f.x * st2[128 + d] + st2[192 + d];
          float v1 = f.y * st2[129 + d] + st2[193 + d];
          float v2 = f.z * st2[130 + d] + st2[194 + d];
          float v3 = f.w * st2[131 + d] + st2[195 + d];
          v0 = (v0 >= 0.f) ? v0 : 0.01f * v0;
          v1 = (v1 >= 0.f) ? v1 : 0.01f * v1;
          v2 = (v2 >= 0.f) ? v2 : 0.01f * v2;
          v3 = (v3 >= 0.f) ? v3 : 0.01f * v3;
          t.h[j * 4 + 0] = (bf16)v0; t.h[j * 4 + 1] = (bf16)v1;
          t.h[j * 4 + 2] = (bf16)v2; t.h[j * 4 + 3] = (bf16)v3;
        }
      } else {
        t.u[0] = uint4{0, 0, 0, 0}; t.u[1] = uint4{0, 0, 0, 0};
      }
      *(uint4*)&As[r][c * 16] = t.u[0];
      *(uint4*)&As[r][c * 16 + 8] = t.u[1];
      const float4* wp = (const float4*)(fw1 + r * 320 + 256 + c * 16);
#pragma unroll
      for (int j = 0; j < 2; ++j) {
        float4 f0 = wp[j * 2], f1 = wp[j * 2 + 1];
        union { bf16 h[8]; uint4 u; } tw;
        tw.h[0] = (bf16)f0.x; tw.h[1] = (bf16)f0.y; tw.h[2] = (bf16)f0.z; tw.h[3] = (bf16)f0.w;
        tw.h[4] = (bf16)f1.x; tw.h[5] = (bf16)f1.y; tw.h[6] = (bf16)f1.z; tw.h[7] = (bf16)f1.w;
        *(uint4*)&Bs[r][c * 16 + j * 8] = tw.u;
      }
    }
    __syncthreads();
    int kmax = (seg == 0) ? 128 : 64;
    for (int k0 = 0; k0 < kmax; k0 += 32) {
      bf16x8 a = *(const bf16x8*)&As[w * 16 + m][k0 + quad * 8];
#pragma unroll
      for (int t = 0; t < 4; ++t) {
        bf16x8 b = *(const bf16x8*)&Bs[t * 16 + m][k0 + quad * 8];
        acc[t] = __builtin_amdgcn_mfma_f32_16x16x32_bf16(a, b, acc[t], 0, 0, 0);
      }
    }
  }

#pragma unroll
  for (int t = 0; t < 4; ++t) {
    int o = t * 16 + m;
    float bv = fb1[o];
    float s = 0.f, q = 0.f;
#pragma unroll
    for (int r4 = 0; r4 < 4; ++r4) {
      int node = nbase + w * 16 + quad * 4 + r4;
      if (node < n) {
        float v = acc[t][r4] + bv;
        hf[(size_t)node * 64 + o] = (bf16)v;
        s += v;
        q += v * v;
      }
    }
    atomicAdd(&s_sum[o], s);
    atomicAdd(&s_sq[o], q);
  }
  __syncthreads();
  if (tid < 64) {
    atomicAdd(&stats[tid], s_sum[tid]);
    atomicAdd(&stats[64 + tid], s_sq[tid]);
  }
}

// ---------------- BN finalize: scale/shift ----------------
__global__ void bn_finalize_kernel(float* __restrict__ st, const float* __restrict__ g,
                                   const float* __restrict__ be, float inv_n) {
  int o = threadIdx.x;
  if (o < 64) {
    float mean = st[o] * inv_n;
    float var = st[64 + o] * inv_n - mean * mean;
    float sc = g[o] * rsqrtf(var + 1e-5f);
    st[128 + o] = sc;
    st[192 + o] = be[o] - mean * sc;
  }
}

// ---------------- head: sigmoid(leaky(bn(hf)) @ fw2^T + fb2) ----------------
__global__ __launch_bounds__(256) void final_out_kernel(const bf16* __restrict__ hf,
                                                        const float* __restrict__ st,
                                                        const float* __restrict__ fw2,
                                                        const float* __restrict__ fb2,
                                                        float* __restrict__ out, int n) {
  int lane = threadIdx.x & 63;
  int node = blockIdx.x * 4 + (threadIdx.x >> 6);
  if (node >= n) return;
  float v = (float)hf[(size_t)node * 64 + lane] * st[128 + lane] + st[192 + lane];
  v = (v >= 0.f) ? v : 0.01f * v;
  v *= fw2[lane];
#pragma unroll
  for (int off = 32; off > 0; off >>= 1) v += __shfl_xor(v, off);
  if (lane == 0) out[node] = 1.f / (1.f + expf(-(v + fb2[0])));
}

extern "C" void kernel_launch(void* const* d_in, const int* in_sizes, int n_in,
                              void* d_out, int out_size, void* d_ws, size_t ws_size,
                              hipStream_t stream) {
  const int* node_deg = (const int*)d_in[0];
  const int* node_lab = (const int*)d_in[1];
  const int* ei = (const int*)d_in[2];
  const float* emb_deg = (const float*)d_in[3];
  const float* emb_lab = (const float*)d_in[4];
  const float* w0 = (const float*)d_in[5];
  const float* b0 = (const float*)d_in[6];
  const float* g0 = (const float*)d_in[7];
  const float* be0 = (const float*)d_in[8];
  const float* w1 = (const float*)d_in[9];
  const float* b1 = (const float*)d_in[10];
  const float* g1 = (const float*)d_in[11];
  const float* be1 = (const float*)d_in[12];
  const float* w2 = (const float*)d_in[13];
  const float* b2 = (const float*)d_in[14];
  const float* g2 = (const float*)d_in[15];
  const float* be2 = (const float*)d_in[16];
  const float* fw1 = (const float*)d_in[17];
  const float* fb1 = (const float*)d_in[18];
  const float* fg = (const float*)d_in[19];
  const float* fbe = (const float*)d_in[20];
  const float* fw2 = (const float*)d_in[21];
  const float* fb2 = (const float*)d_in[22];

  const int N = in_sizes[0];
  const int E = in_sizes[2] / 2;
  const int* src = ei;
  const int* dst = ei + E;
  const int nbuck = (N + 127) >> 7;

  char* ws = (char*)d_ws;
  size_t off = 0;
  auto alloc = [&](size_t bytes) {
    void* p = ws + off;
    off += (bytes + 255) & ~(size_t)255;
    return p;
  };
  bf16* x0 = (bf16*)alloc((size_t)N * 128 * 2);
  bf16* z1 = (bf16*)alloc((size_t)N * 64 * 2);
  bf16* z2 = (bf16*)alloc((size_t)N * 64 * 2);
  float* h = (float*)alloc((size_t)N * 64 * 4);
  bf16* y = (bf16*)alloc((size_t)N * 64 * 2);  // also reused as hf
  int* rowptr = (int*)alloc((size_t)(N + 1) * 4);
  int* cursor = (int*)alloc((size_t)N * 4);
  int* counts = (int*)alloc((size_t)N * 4);
  int* colidx = (int*)alloc((size_t)E * 4);
  int2* binned = (int2*)alloc((size_t)E * 8);
  int* bcur = (int*)alloc((size_t)nbuck * 4);
  int* bsums = (int*)alloc(64 * 4);
  int* boffs = (int*)alloc(64 * 4);
  float* stats = (float*)alloc(4 * 256 * 4);

  hipMemsetAsync(counts, 0, (size_t)N * 4, stream);
  hipMemsetAsync(stats, 0, 4 * 256 * 4, stream);

  embed_kernel<<<(N * 16 + 255) / 256, 256, 0, stream>>>(node_deg, node_lab, emb_deg,
                                                         emb_lab, x0, N);
  hist_kernel<<<(E + 255) / 256, 256, 0, stream>>>(dst, counts, E);
  int nb = (N + 2047) / 2048;
  scan1_kernel<<<nb, 256, 0, stream>>>(counts, rowptr, bsums, N);
  scan2_kernel<<<1, 64, 0, stream>>>(bsums, boffs, nb);
  scan3_kernel<<<(N + 255) / 256, 256, 0, stream>>>(rowptr, boffs, N);
  cursor_kernel<<<(N + 255) / 256, 256, 0, stream>>>(cursor, bcur, rowptr, N, nbuck);
  binpass_kernel<<<(E + 255) / 256, 256, 0, stream>>>(src, dst, bcur, binned, E);
  scatter2_kernel<<<(E + 255) / 256, 256, 0, stream>>>(binned, cursor, colidx, E);

  int ngrid = (N + 63) / 64;
  int ggrid = 2048;

  // layer 0
  mfma_gemm0<<<ngrid, 256, 0, stream>>>(x0, w0, y, N);
  gather_kernel<<<ggrid, 256, 0, stream>>>(y, rowptr, colidx, b0, h, stats, N);
  bn_finalize_kernel<<<1, 64, 0, stream>>>(stats, g0, be0, 1.0f / N);
  // layer 1
  mfma_gemm_bn<<<ngrid, 256, 0, stream>>>(h, stats, w1, z1, y, N);
  gather_kernel<<<ggrid, 256, 0, stream>>>(y, rowptr, colidx, b1, h, stats + 256, N);
  bn_finalize_kernel<<<1, 64, 0, stream>>>(stats + 256, g1, be1, 1.0f / N);
  // layer 2
  mfma_gemm_bn<<<ngrid, 256, 0, stream>>>(h, stats + 256, w2, z2, y, N);
  gather_kernel<<<ggrid, 256, 0, stream>>>(y, rowptr, colidx, b2, h, stats + 512, N);
  bn_finalize_kernel<<<1, 64, 0, stream>>>(stats + 512, g2, be2, 1.0f / N);
  // final MLP 320 -> 64 (z3 inline from h2); hf reuses y buffer (bf16)
  mfma_final<<<ngrid, 256, 0, stream>>>(x0, z1, z2, h, stats + 512, fw1, fb1, y,
                                        stats + 768, N);
  bn_finalize_kernel<<<1, 64, 0, stream>>>(stats + 768, fg, fbe, 1.0f / N);
  final_out_kernel<<<(N + 3) / 4, 256, 0, stream>>>(y, stats + 768, fw2, fb2,
                                                    (float*)d_out, N);
}